// Round 11
// baseline (165.147 us; speedup 1.0000x reference)
//
#include <hip/hip_runtime.h>
#include <stddef.h>

// Output layout (fp32):
//   recon    [200,4096,64] @ 0
//   z0_mean  [4096,3]      @ 52428800
//   z0_logvar[4096,3]      @ 52441088
//   traj     [200,4096,3]  @ 52453376
#define OFF_MEAN 52428800
#define OFF_LV   52441088
#define OFF_TRAJ 52453376

typedef _Float16 f16x8 __attribute__((ext_vector_type(8)));
typedef _Float16 f16x4 __attribute__((ext_vector_type(4)));
typedef _Float16 f16x2 __attribute__((ext_vector_type(2)));
typedef float    f32x4 __attribute__((ext_vector_type(4)));

#define MFMA16(a, b, c) __builtin_amdgcn_mfma_f32_16x16x32_f16((a), (b), (c), 0, 0, 0)

// fast transcendentals: v_exp_f32 + v_rcp_f32 (error ~1e-6, far below budget)
__device__ __forceinline__ float sigm_(float x) {
    float e = __builtin_amdgcn_exp2f(x * -1.442695041f);
    return __builtin_amdgcn_rcpf(1.f + e);
}
__device__ __forceinline__ float tanh_(float x) {
    float e = __builtin_amdgcn_exp2f(x * 2.885390082f);
    return 1.f - 2.f * __builtin_amdgcn_rcpf(e + 1.f);
}
__device__ __forceinline__ float dot4_(float4 a, float4 b) {
    return a.x * b.x + a.y * b.y + a.z * b.z + a.w * b.w;
}

// ---------------------------------------------------------------- GRU (MFMA, gate-aligned, single-f16)
// (unchanged from round 9)
__global__ __launch_bounds__(512, 2) void k_gru(
    const float* __restrict__ obs, const float* __restrict__ eps,
    const float* __restrict__ Wih, const float* __restrict__ Whh,
    const float* __restrict__ bih, const float* __restrict__ bhh,
    const float* __restrict__ meanW, const float* __restrict__ meanB,
    const float* __restrict__ lvW,  const float* __restrict__ lvB,
    float* __restrict__ o_mean, float* __restrict__ o_lv, float* __restrict__ z0)
{
    __shared__ alignas(16) unsigned short h_s[2][2048];  // [16][128] f16, 4-bit swizzle, dbuf
    __shared__ alignas(16) unsigned short x_s[2][1024];  // [16][64]  f16, 3-bit swizzle, dbuf
    __shared__ alignas(16) float hm_s[16 * 132];
    __shared__ float mb_s[96];

    const int tid  = threadIdx.x;
    const int b0   = blockIdx.x * 16;
    const int lane = tid & 63, wv = tid >> 6;
    const int lrow = lane & 15, lkb = lane >> 4;
    const int swX  = (lrow & 7) << 4;
    const int swH  = lrow << 4;
    const int u    = wv * 16 + lrow;

    const float bR  = bih[u]       + bhh[u];
    const float bZ  = bih[128 + u] + bhh[128 + u];
    const float bNi = bih[256 + u];
    const float bNh = bhh[256 + u];

    f16x8 wihf[3][2];
    #pragma unroll
    for (int g = 0; g < 3; ++g) {
        int col = g * 128 + u;
        #pragma unroll
        for (int ks = 0; ks < 2; ++ks) {
            const float* wp = Wih + col * 64 + ks * 32 + lkb * 8;
            float4 a = *(const float4*)wp, b = *(const float4*)(wp + 4);
            float tmp[8] = {a.x, a.y, a.z, a.w, b.x, b.y, b.z, b.w};
            f16x8 hv;
            #pragma unroll
            for (int j = 0; j < 8; ++j) hv[j] = (_Float16)tmp[j];
            wihf[g][ks] = hv;
        }
    }
    f16x8 whhh[3][4];
    #pragma unroll
    for (int g = 0; g < 3; ++g) {
        int col = g * 128 + u;
        #pragma unroll
        for (int ks = 0; ks < 4; ++ks) {
            const float* wp = Whh + col * 128 + ks * 32 + lkb * 8;
            float4 a = *(const float4*)wp, b = *(const float4*)(wp + 4);
            float tmp[8] = {a.x, a.y, a.z, a.w, b.x, b.y, b.z, b.w};
            f16x8 hv;
            #pragma unroll
            for (int j = 0; j < 8; ++j) hv[j] = (_Float16)tmp[j];
            whhh[g][ks] = hv;
        }
    }

    for (int i = tid; i < 2048; i += 512) h_s[0][i] = 0;
    const int srow = tid >> 4, skq = (tid & 15) * 4;
    const int sxb  = srow * 128 + ((skq * 2) ^ ((srow & 7) << 4));
    float4 xn;
    if (tid < 256) {
        xn = *(const float4*)(obs + ((size_t)0 * 4096 + b0 + srow) * 64 + skq);
        f16x4 vh = {(_Float16)xn.x, (_Float16)xn.y, (_Float16)xn.z, (_Float16)xn.w};
        *(f16x4*)((char*)x_s[0] + sxb) = vh;
    }
    f32x4 hold = {0.f, 0.f, 0.f, 0.f};
    __syncthreads();

    for (int t = 0; t < 50; ++t) {
        const int cur = t & 1, nxt = cur ^ 1;
        char* x_c = (char*)x_s[cur];
        char* h_c = (char*)h_s[cur];

        if (tid < 256) {
            int tt = (t < 49) ? t + 1 : t;
            xn = *(const float4*)(obs + ((size_t)tt * 4096 + b0 + srow) * 64 + skq);
        }

        f16x8 xh[2], hh[4];
        #pragma unroll
        for (int ks = 0; ks < 2; ++ks) {
            int off = lrow * 128 + ((ks * 64 + lkb * 16) ^ swX);
            xh[ks] = *(const f16x8*)(x_c + off);
        }
        #pragma unroll
        for (int ks = 0; ks < 4; ++ks) {
            int off = lrow * 256 + ((ks * 64 + lkb * 16) ^ swH);
            hh[ks] = *(const f16x8*)(h_c + off);
        }

        f32x4 z4 = {0.f, 0.f, 0.f, 0.f};
        f32x4 aR = z4, aZ = z4, aNi = z4, aNh = z4;
        #pragma unroll
        for (int ks = 0; ks < 2; ++ks) {
            aR  = MFMA16(xh[ks], wihf[0][ks], aR);
            aZ  = MFMA16(xh[ks], wihf[1][ks], aZ);
            aNi = MFMA16(xh[ks], wihf[2][ks], aNi);
        }
        #pragma unroll
        for (int ks = 0; ks < 4; ++ks) {
            aR  = MFMA16(hh[ks], whhh[0][ks], aR);
            aZ  = MFMA16(hh[ks], whhh[1][ks], aZ);
            aNh = MFMA16(hh[ks], whhh[2][ks], aNh);
        }

        char* hn_c = (char*)h_s[nxt];
        #pragma unroll
        for (int i = 0; i < 4; ++i) {
            float r  = sigm_(aR[i] + bR);
            float zg = sigm_(aZ[i] + bZ);
            float n  = tanh_(aNi[i] + bNi + r * (aNh[i] + bNh));
            float hv = (1.f - zg) * n + zg * hold[i];
            hold[i] = hv;
            int ri = lkb * 4 + i;
            int hb = ri * 256 + ((u * 2) ^ (ri << 4));
            *(_Float16*)(hn_c + hb) = (_Float16)hv;
        }

        if (tid < 256 && t < 49) {
            f16x4 vh = {(_Float16)xn.x, (_Float16)xn.y, (_Float16)xn.z, (_Float16)xn.w};
            *(f16x4*)((char*)x_s[nxt] + sxb) = vh;
        }
        __syncthreads();
    }

    #pragma unroll
    for (int i = 0; i < 4; ++i)
        hm_s[(lkb * 4 + i) * 132 + u] = hold[i];
    __syncthreads();

    if (tid < 96) {
        int rr = tid / 6, c = tid - rr * 6, j = (c < 3) ? c : c - 3;
        const float* W = (c < 3) ? meanW : lvW;
        const float* B = (c < 3) ? meanB : lvB;
        float acc = B[j];
        const float4* W4 = (const float4*)(W + j * 128);
        const float4* h4 = (const float4*)(hm_s + rr * 132);
        #pragma unroll 4
        for (int kc = 0; kc < 32; ++kc) acc += dot4_(W4[kc], h4[kc]);
        mb_s[rr * 6 + c] = acc;
    }
    __syncthreads();
    if (tid < 48) {
        int rr = tid / 3, j = tid - rr * 3;
        int gb = b0 + rr;
        float m  = mb_s[rr * 6 + j];
        float lv = mb_s[rr * 6 + j + 3];
        o_mean[gb * 3 + j] = m;
        o_lv[gb * 3 + j]   = lv;
        z0[gb * 3 + j]     = m + eps[gb * 3 + j] * __expf(0.5f * lv);
    }
}

// ---------------------------------------------------------------- ODE + decoder (fused, 4 rows/block)
// 1024 blocks x 256 threads (4 waves), 4 batch rows/block -> ~4 blocks/CU:
// 4 independent RK chains per CU overlap each other's barrier/latency stalls.
// RK4 h=0.16 (12 steps) + final 0.07; start-inclusive dense windows.
__global__ __launch_bounds__(256, 4) void k_odec(
    const float* __restrict__ dW1, const float* __restrict__ db1,
    const float* __restrict__ dW2, const float* __restrict__ db2,
    const float* __restrict__ dW3, const float* __restrict__ db3,
    const float* __restrict__ decW1, const float* __restrict__ decb1,
    const float* __restrict__ decW2, const float* __restrict__ decb2,
    const float* __restrict__ z0, float* __restrict__ traj, float* __restrict__ recon)
{
    __shared__ alignas(16) unsigned short h1h_s[2048];    // [16][128] f16, swizzled (rows 4..15 = 0)
    __shared__ alignas(16) unsigned short hd_s[4096];     // [64][64] f16, swizzled
    __shared__ alignas(16) float h2f[4 * 104];
    __shared__ alignas(16) float W3s[312];
    __shared__ alignas(16) float zbuf[64 * 4];
    __shared__ float w1ds[192], b1ds[64];
    __shared__ float b2s[100], b3s[3];
    __shared__ float fparts[12];

    const int tid  = threadIdx.x;
    const int b0   = blockIdx.x * 4;
    const int lane = tid & 63, wv = tid >> 6;
    const int r    = tid >> 6;             // RK row owned by this thread (0..3)
    char* h1h_c = (char*)h1h_s;
    char* hd_c  = (char*)hd_s;

    for (int i = tid; i < 1024; i += 256)
        ((unsigned int*)h1h_c)[i] = 0u;
    if (tid < 16) h2f[(tid >> 2) * 104 + 100 + (tid & 3)] = 0.f;
    for (int i = tid; i < 312; i += 256) {
        int j = i / 104, k = i - j * 104;
        W3s[i] = (k < 100) ? dW3[j * 100 + k] : 0.f;
    }
    if (tid < 100) b2s[tid] = db2[tid];
    if (tid < 3)   b3s[tid] = db3[tid];
    if (tid < 192) w1ds[tid] = decW1[tid];
    if (tid < 64)  b1ds[tid] = decb1[tid];

    // ODE stage-1 weights in registers (2 k-rows per thread, 64 threads cover 128)
    float w1r[6], b1r[2];
    {
        int k0 = (tid & 63) * 2;
        #pragma unroll
        for (int i = 0; i < 2; ++i) {
            int k = k0 + i;
            if (k < 100) {
                w1r[3 * i + 0] = dW1[k * 3 + 0];
                w1r[3 * i + 1] = dW1[k * 3 + 1];
                w1r[3 * i + 2] = dW1[k * 3 + 2];
                b1r[i] = db1[k];
            } else {
                w1r[3 * i + 0] = 0.f; w1r[3 * i + 1] = 0.f; w1r[3 * i + 2] = 0.f;
                b1r[i] = 0.f;
            }
        }
    }
    const int lrow = lane & 15, lkb = lane >> 4;
    const int swA  = (lrow & 7) << 4;

    // ODE W2 B-fragments (f16), 2 col-tiles per wave
    f16x8 w2h[2][4];
    #pragma unroll
    for (int tile = 0; tile < 2; ++tile) {
        int col = (wv * 2 + tile) * 16 + lrow;
        #pragma unroll
        for (int ks = 0; ks < 4; ++ks) {
            f16x8 hv;
            #pragma unroll
            for (int j = 0; j < 8; ++j) {
                int k = ks * 32 + lkb * 8 + j;
                float v = (col < 100 && k < 100) ? dW2[col * 100 + k] : 0.f;
                hv[j] = (_Float16)v;
            }
            w2h[tile][ks] = hv;
        }
    }
    // decoder W2 B-fragments (f16), one col-tile per wave
    const int colD = wv * 16 + lrow;
    f16x8 dbh[2];
    #pragma unroll
    for (int ks = 0; ks < 2; ++ks) {
        const float* wp = decW2 + colD * 64 + ks * 32 + lkb * 8;
        float4 a = *(const float4*)wp, b = *(const float4*)(wp + 4);
        float tmp[8] = {a.x, a.y, a.z, a.w, b.x, b.y, b.z, b.w};
        f16x8 hv;
        #pragma unroll
        for (int j = 0; j < 8; ++j) hv[j] = (_Float16)tmp[j];
        dbh[ks] = hv;
    }
    const float dbo = decb2[colD];

    float yv0 = z0[(b0 + r) * 3 + 0];
    float yv1 = z0[(b0 + r) * 3 + 1];
    float yv2 = z0[(b0 + r) * 3 + 2];
    float ka0, ka1, ka2, k10, k11, k12, yn0, yn1, yn2;
    __syncthreads();

#define FEVAL(yt0_, yt1_, yt2_)                                                  \
    do {                                                                          \
        { /* phase A: h1 = tanh(W1 y + b1), rows 0..3, 2 units/thread */          \
            int k0 = (tid & 63) * 2;                                              \
            f16x2 hw;                                                             \
            _Pragma("unroll")                                                     \
            for (int i = 0; i < 2; ++i) {                                         \
                float acc = b1r[i] + w1r[3 * i] * (yt0_)                          \
                          + w1r[3 * i + 1] * (yt1_) + w1r[3 * i + 2] * (yt2_);    \
                hw[i] = (_Float16)tanh_(acc);                                     \
            }                                                                     \
            int off = r * 256 + ((k0 * 2) ^ (r << 4));                            \
            *(f16x2*)(h1h_c + off) = hw;                                          \
        }                                                                         \
        __syncthreads();                                                          \
        { /* phase B: MFMA h2acc = h1 @ W2^T; phase C: tanh -> h2f (rows 0..3) */ \
            f16x8 ah[4];                                                          \
            _Pragma("unroll")                                                     \
            for (int ks = 0; ks < 4; ++ks) {                                      \
                int off = lrow * 256 + ((ks * 64 + lkb * 16) ^ swA);              \
                ah[ks] = *(const f16x8*)(h1h_c + off);                            \
            }                                                                     \
            f32x4 acc0 = {0.f, 0.f, 0.f, 0.f}, acc1 = {0.f, 0.f, 0.f, 0.f};       \
            _Pragma("unroll")                                                     \
            for (int ks = 0; ks < 4; ++ks) {                                      \
                acc0 = MFMA16(ah[ks], w2h[0][ks], acc0);                          \
                acc1 = MFMA16(ah[ks], w2h[1][ks], acc1);                          \
            }                                                                     \
            if (lkb == 0) {                                                       \
                _Pragma("unroll")                                                 \
                for (int tile = 0; tile < 2; ++tile) {                            \
                    int col = (wv * 2 + tile) * 16 + lrow;                        \
                    f32x4 a = tile ? acc1 : acc0;                                 \
                    if (col < 100) {                                              \
                        float bb = b2s[col];                                      \
                        _Pragma("unroll")                                         \
                        for (int i = 0; i < 4; ++i)                               \
                            h2f[i * 104 + col] = tanh_(a[i] + bb);                \
                    }                                                             \
                }                                                                 \
            }                                                                     \
        }                                                                         \
        __syncthreads();                                                          \
        { /* phase D: f = W3 h2 + b3 via quarter-dots + shfl reduce */            \
            if (tid < 48) {                                                       \
                int rr = tid / 12, rem = tid - rr * 12, j = rem >> 2, qc = rem & 3;\
                const float4* Wj = (const float4*)(W3s + j * 104);                \
                const float4* Hr = (const float4*)(h2f + rr * 104);               \
                float acc = 0.f;                                                  \
                _Pragma("unroll")                                                 \
                for (int kc = 0; kc < 7; ++kc) {                                  \
                    int k = qc + kc * 4;                                          \
                    if (k < 26) acc += dot4_(Wj[k], Hr[k]);                       \
                }                                                                 \
                acc += __shfl_xor(acc, 1);                                        \
                acc += __shfl_xor(acc, 2);                                        \
                if (qc == 0) fparts[rr * 3 + j] = acc + b3s[j];                   \
            }                                                                     \
        }                                                                         \
        __syncthreads();                                                          \
    } while (0)

    FEVAL(yv0, yv1, yv2);

    #pragma unroll 1
    for (int s = 0; s < 13; ++s) {
        const int   npts = (s < 12) ? 16 : 8;           // dense points this step
        const float hh   = (s < 12) ? 0.16f : 0.07f;
        const int   t0   = s * 16;
        const float invN = (s < 12) ? 0.0625f : (1.f / 7.f);

        // RK4
        float f0_ = fparts[r * 3 + 0], f1_ = fparts[r * 3 + 1], f2_ = fparts[r * 3 + 2];
        k10 = f0_; k11 = f1_; k12 = f2_;
        ka0 = f0_; ka1 = f1_; ka2 = f2_;
        float yt0 = yv0 + 0.5f * hh * f0_, yt1 = yv1 + 0.5f * hh * f1_, yt2 = yv2 + 0.5f * hh * f2_;
        FEVAL(yt0, yt1, yt2);
        f0_ = fparts[r * 3 + 0]; f1_ = fparts[r * 3 + 1]; f2_ = fparts[r * 3 + 2];
        ka0 += 2.f * f0_; ka1 += 2.f * f1_; ka2 += 2.f * f2_;
        yt0 = yv0 + 0.5f * hh * f0_; yt1 = yv1 + 0.5f * hh * f1_; yt2 = yv2 + 0.5f * hh * f2_;
        FEVAL(yt0, yt1, yt2);
        f0_ = fparts[r * 3 + 0]; f1_ = fparts[r * 3 + 1]; f2_ = fparts[r * 3 + 2];
        ka0 += 2.f * f0_; ka1 += 2.f * f1_; ka2 += 2.f * f2_;
        yt0 = yv0 + hh * f0_; yt1 = yv1 + hh * f1_; yt2 = yv2 + hh * f2_;
        FEVAL(yt0, yt1, yt2);
        f0_ = fparts[r * 3 + 0]; f1_ = fparts[r * 3 + 1]; f2_ = fparts[r * 3 + 2];
        ka0 += f0_; ka1 += f1_; ka2 += f2_;
        const float h6 = hh * (1.f / 6.f);
        yn0 = yv0 + h6 * ka0; yn1 = yv1 + h6 * ka1; yn2 = yv2 + h6 * ka2;
        FEVAL(yn0, yn1, yn2);
        float fn0 = fparts[r * 3 + 0], fn1 = fparts[r * 3 + 1], fn2 = fparts[r * 3 + 2];

        // phase Z: dense output -> traj (global) + zbuf (LDS)
        {
            int tot = 3 * npts;
            for (int ii = (tid & 63); ii < tot; ii += 64) {
                int q = ii / 3, j = ii - q * 3;
                float ysj = (j == 0) ? yv0 : (j == 1) ? yv1 : yv2;
                float f0j = (j == 0) ? k10 : (j == 1) ? k11 : k12;
                float ynj = (j == 0) ? yn0 : (j == 1) ? yn1 : yn2;
                float fnj = (j == 0) ? fn0 : (j == 1) ? fn1 : fn2;
                float th  = (float)q * invN;
                float th2 = th * th, th3 = th2 * th;
                float ca = 2.f * th3 - 3.f * th2 + 1.f;
                float cb = th3 - 2.f * th2 + th;
                float cc = 3.f * th2 - 2.f * th3;
                float cd = th3 - th2;
                float v = ca * ysj + cb * hh * f0j + cc * ynj + cd * hh * fnj;
                traj[((size_t)(t0 + q) * 4096 + b0 + r) * 3 + j] = v;
                zbuf[(q * 4 + r) * 4 + j] = v;
            }
        }
        __syncthreads();

        // phase H: hd = relu(W1d z + b1d) -> f16 swizzled LDS (p = pt, 16 units/thread)
        {
            const int p  = tid >> 2;
            const int u0 = (tid & 3) * 16;
            if (p < npts * 4) {
                const float z0v = zbuf[p * 4 + 0], z1v = zbuf[p * 4 + 1], z2v = zbuf[p * 4 + 2];
                const int sw = (p & 7) << 4;
                #pragma unroll
                for (int c = 0; c < 4; ++c) {
                    f16x4 hh_;
                    #pragma unroll
                    for (int i = 0; i < 4; ++i) {
                        int u = u0 + c * 4 + i;
                        float acc = b1ds[u] + w1ds[u * 3 + 0] * z0v
                                            + w1ds[u * 3 + 1] * z1v
                                            + w1ds[u * 3 + 2] * z2v;
                        hh_[i] = (_Float16)fmaxf(acc, 0.f);
                    }
                    int off = p * 128 + (((u0 + c * 4) * 2) ^ sw);
                    *(f16x4*)(hd_c + off) = hh_;
                }
            }
        }
        __syncthreads();

        // phase M: recon = hd @ decW2^T + b2  (wave wv owns cols wv*16..+15)
        {
            const int nrt = (npts * 4) >> 4;
            for (int rt = 0; rt < nrt; ++rt) {
                f16x8 a0, a1;
                {
                    int base = (rt * 16 + lrow) * 128;
                    a0 = *(const f16x8*)(hd_c + base + ((0 + lkb * 16) ^ swA));
                    a1 = *(const f16x8*)(hd_c + base + ((64 + lkb * 16) ^ swA));
                }
                f32x4 acc = {0.f, 0.f, 0.f, 0.f};
                acc = MFMA16(a0, dbh[0], acc);
                acc = MFMA16(a1, dbh[1], acc);
                #pragma unroll
                for (int i = 0; i < 4; ++i) {
                    int pr = rt * 16 + lkb * 4 + i;
                    int q = pr >> 2, row = pr & 3;
                    recon[((size_t)(t0 + q) * 4096 + b0 + row) * 64 + colD] = acc[i] + dbo;
                }
            }
        }
        yv0 = yn0; yv1 = yn1; yv2 = yn2;
    }
#undef FEVAL
}

extern "C" void kernel_launch(void* const* d_in, const int* in_sizes, int n_in,
                              void* d_out, int out_size, void* d_ws, size_t ws_size,
                              hipStream_t stream)
{
    const float* obs   = (const float*)d_in[0];
    const float* eps   = (const float*)d_in[1];
    const float* Wih   = (const float*)d_in[2];
    const float* Whh   = (const float*)d_in[3];
    const float* bih   = (const float*)d_in[4];
    const float* bhh   = (const float*)d_in[5];
    const float* meanW = (const float*)d_in[6];
    const float* meanB = (const float*)d_in[7];
    const float* lvW   = (const float*)d_in[8];
    const float* lvB   = (const float*)d_in[9];
    const float* dW1   = (const float*)d_in[10];
    const float* db1   = (const float*)d_in[11];
    const float* dW2   = (const float*)d_in[12];
    const float* db2   = (const float*)d_in[13];
    const float* dW3   = (const float*)d_in[14];
    const float* db3   = (const float*)d_in[15];
    const float* decW1 = (const float*)d_in[16];
    const float* decb1 = (const float*)d_in[17];
    const float* decW2 = (const float*)d_in[18];
    const float* decb2 = (const float*)d_in[19];

    float* out   = (float*)d_out;
    float* recon = out;
    float* omean = out + OFF_MEAN;
    float* olv   = out + OFF_LV;
    float* traj  = out + OFF_TRAJ;
    float* z0    = (float*)d_ws;

    k_gru<<<dim3(256), dim3(512), 0, stream>>>(obs, eps, Wih, Whh, bih, bhh,
                                               meanW, meanB, lvW, lvB, omean, olv, z0);
    k_odec<<<dim3(1024), dim3(256), 0, stream>>>(dW1, db1, dW2, db2, dW3, db3,
                                                 decW1, decb1, decW2, decb2,
                                                 z0, traj, recon);
}